// Round 10
// baseline (514.993 us; speedup 1.0000x reference)
//
#include <hip/hip_runtime.h>
#include <hip/hip_fp16.h>

#define BN_EPS 1e-5f
#define CHUNK 2048            // edges per bucketing block (hist and scatter must match)
#define BBITS 7               // 128 nodes per bucket
#define NCH 8                 // feature chunks (16 features = 32 B each)

typedef _Float16 half8 __attribute__((ext_vector_type(8)));
typedef float f32x4 __attribute__((ext_vector_type(4)));

__device__ __forceinline__ float4 f4zero() { return make_float4(0.f, 0.f, 0.f, 0.f); }

// ---------------- bucket-sort CSR build (no device-scope returning atomics) ----------------

__global__ __launch_bounds__(256) void k_bucket_hist(const int* __restrict__ dst,
                                                     int* __restrict__ tableT,
                                                     int nA, int nbuck, int e) {
    __shared__ int h[1024];
    int blk = blockIdx.x, tid = threadIdx.x;
    for (int k = tid; k < 1024; k += 256) h[k] = 0;
    __syncthreads();
    int base = blk * CHUNK;
    if (base + CHUNK <= e && (e & 3) == 0) {
        const int4* d4 = (const int4*)(dst + base);
#pragma unroll
        for (int t = 0; t < CHUNK / 1024; ++t) {
            int4 d = d4[t * 256 + tid];
            atomicAdd(&h[d.x >> BBITS], 1);
            atomicAdd(&h[d.y >> BBITS], 1);
            atomicAdd(&h[d.z >> BBITS], 1);
            atomicAdd(&h[d.w >> BBITS], 1);
        }
    } else {
        for (int i = base + tid; i < e && i < base + CHUNK; i += 256)
            atomicAdd(&h[dst[i] >> BBITS], 1);
    }
    __syncthreads();
    for (int k = tid; k < nbuck; k += 256)
        tableT[(size_t)k * nA + blk] = h[k];
}

__global__ __launch_bounds__(256) void k_bucket_scatter(const int* __restrict__ src,
                                                        const int* __restrict__ dst,
                                                        const int* __restrict__ tableT,
                                                        int2* __restrict__ bed,
                                                        int nA, int nbuck, int e) {
    __shared__ int cur[1024];
    int blk = blockIdx.x, tid = threadIdx.x;
    for (int k = tid; k < nbuck; k += 256)
        cur[k] = tableT[(size_t)k * nA + blk];
    __syncthreads();
    int base = blk * CHUNK;
    if (base + CHUNK <= e && (e & 3) == 0) {
        const int4* s4 = (const int4*)(src + base);
        const int4* d4 = (const int4*)(dst + base);
#pragma unroll
        for (int t = 0; t < CHUNK / 1024; ++t) {
            int4 s = s4[t * 256 + tid];
            int4 d = d4[t * 256 + tid];
            int p0 = atomicAdd(&cur[d.x >> BBITS], 1); bed[p0] = make_int2(s.x, d.x);
            int p1 = atomicAdd(&cur[d.y >> BBITS], 1); bed[p1] = make_int2(s.y, d.y);
            int p2 = atomicAdd(&cur[d.z >> BBITS], 1); bed[p2] = make_int2(s.z, d.z);
            int p3 = atomicAdd(&cur[d.w >> BBITS], 1); bed[p3] = make_int2(s.w, d.w);
        }
    } else {
        for (int i = base + tid; i < e && i < base + CHUNK; i += 256) {
            int d = dst[i];
            int p = atomicAdd(&cur[d >> BBITS], 1);
            bed[p] = make_int2(src[i], d);
        }
    }
}

__global__ __launch_bounds__(256) void k_bucket_rank(const int2* __restrict__ bed,
                                                     const int* __restrict__ tableT,
                                                     int* __restrict__ brank,
                                                     int* __restrict__ counts,
                                                     float* __restrict__ dinv,
                                                     int nA, int nbuck, int n, int e) {
    __shared__ int lcnt[128];
    int b = blockIdx.x, tid = threadIdx.x;
    if (tid < 128) lcnt[tid] = 0;
    __syncthreads();
    int start = tableT[(size_t)b * nA];
    int end = (b + 1 < nbuck) ? tableT[(size_t)(b + 1) * nA] : e;
    for (int i = start + tid; i < end; i += 256) {
        int2 q = bed[i];
        brank[i] = atomicAdd(&lcnt[q.y & ((1 << BBITS) - 1)], 1);
    }
    __syncthreads();
    if (tid < 128) {
        int node = (b << BBITS) + tid;
        if (node < n) {
            int c = lcnt[tid];
            counts[node] = c;
            dinv[node] = rsqrtf((float)(c + 1));
        }
    }
}

template <bool PAD8>
__global__ __launch_bounds__(1024) void k_scan_block(const int* __restrict__ counts,
                                                     int* __restrict__ offs,
                                                     int* __restrict__ partials, int len) {
    __shared__ int s[1024];
    int t = threadIdx.x;
    int gid = blockIdx.x * 1024 + t;
    int c = (gid < len) ? counts[gid] : 0;
    int v = PAD8 ? ((c + 7) & ~7) : c;
    int x = v;
    s[t] = x;
    __syncthreads();
    for (int d = 1; d < 1024; d <<= 1) {
        int y = (t >= d) ? s[t - d] : 0;
        __syncthreads();
        x += y;
        s[t] = x;
        __syncthreads();
    }
    if (gid < len) offs[gid] = x - v;
    if (t == 1023) partials[blockIdx.x] = x;
}

__global__ __launch_bounds__(1024) void k_scan_partials(int* __restrict__ partials, int nb) {
    __shared__ int s[1024];
    int t = threadIdx.x;
    int v = (t < nb) ? partials[t] : 0;
    int x = v;
    s[t] = x;
    __syncthreads();
    for (int d = 1; d < 1024; d <<= 1) {
        int y = (t >= d) ? s[t - d] : 0;
        __syncthreads();
        x += y;
        s[t] = x;
        __syncthreads();
    }
    if (t < nb) partials[t] = x - v;
    if (t == nb - 1) partials[nb] = x;
}

__global__ __launch_bounds__(256) void k_scan_add(int* __restrict__ offs,
                                                  const int* __restrict__ partials, int len) {
    int gid = blockIdx.x * 256 + threadIdx.x;
    if (gid < len) offs[gid] += partials[gid >> 10];
    if (gid == 0) offs[len] = partials[(len + 1023) >> 10];
}

__global__ __launch_bounds__(256) void k_fill(int4* __restrict__ er4, int val, int m4) {
    int i = blockIdx.x * 256 + threadIdx.x;
    if (i < m4) er4[i] = make_int4(val, val, val, val);
}

__global__ __launch_bounds__(256) void k_place2(const int2* __restrict__ bed,
                                                const int* __restrict__ brank,
                                                const int* __restrict__ offs,
                                                int* __restrict__ er, int e) {
    int i = (blockIdx.x * 256 + threadIdx.x) * 2;
    if (i + 1 < e) {
        int4 q = *(const int4*)(bed + i);
        int2 r = *(const int2*)(brank + i);
        er[offs[q.y] + r.x] = q.x;
        er[offs[q.w] + r.y] = q.z;
    } else if (i < e) {
        int2 q = bed[i];
        er[offs[q.y] + brank[i]] = q.x;
    }
}

// zero the padding row (node n) in all NCH chunks of the chunk-major f16 buffer
__global__ void k_zero_pad(unsigned int* __restrict__ A, int n) {
    int tid = threadIdx.x;          // 64 threads: c = tid>>3, sub = tid&7
    if (tid < 64) {
        int c = tid >> 3, sub = tid & 7;
        A[((size_t)c * (n + 1) + n) * 8 + sub] = 0u;
    }
}

// ---------------- W pre-pack: f32 [128][128] -> f16 B-fragment order ----------------

__global__ __launch_bounds__(256) void k_packW(const float* __restrict__ W,
                                               _Float16* __restrict__ out) {
    int t = blockIdx.x * 256 + threadIdx.x;
    if (t >= 2048) return;
    int kc = t >> 9;
    int rem = t & 511;
    int ct = rem >> 6;
    int lane = rem & 63;
    int q = lane >> 4;
    int col = ct * 16 + (lane & 15);
    half8 h;
#pragma unroll
    for (int j = 0; j < 8; ++j)
        h[j] = (_Float16)W[(kc * 32 + q * 8 + j) * 128 + col];
    *(half8*)(out + (size_t)t * 8) = h;
}

// ---------------- MFMA GEMM: C (chunk-major f16) = (A @ W) * dinv[row] ----------------
// Output layout: [c][n+1][16 f16] (32 B row-chunks). AF16 input is same layout.

template <bool AF32>
__global__ __launch_bounds__(256) void k_gemm_mfma(const void* __restrict__ Av,
                                                   const _Float16* __restrict__ pW,
                                                   const float* __restrict__ dinv,
                                                   uint2* __restrict__ C, int n) {
    __shared__ char smem[32768];
    uint4* sW = (uint4*)smem;
    int tid = threadIdx.x;

    {
        const uint4* gW = (const uint4*)pW;
#pragma unroll
        for (int i = 0; i < 8; ++i) sW[tid + 256 * i] = gW[tid + 256 * i];
    }
    __syncthreads();

    int wave = tid >> 6, lane = tid & 63;
    int quad = lane >> 4, l16 = lane & 15;
    int row0 = blockIdx.x * 64 + wave * 16;
    int arow = row0 + l16;
    int arowc = (arow < n) ? arow : (n - 1);

    half8 af[4];
    if (AF32) {
        const float* A = (const float*)Av + (size_t)arowc * 128 + quad * 8;
#pragma unroll
        for (int kc = 0; kc < 4; ++kc) {
            float4 lo = *(const float4*)(A + kc * 32);
            float4 hi = *(const float4*)(A + kc * 32 + 4);
            half8 h;
            h[0] = (_Float16)lo.x; h[1] = (_Float16)lo.y;
            h[2] = (_Float16)lo.z; h[3] = (_Float16)lo.w;
            h[4] = (_Float16)hi.x; h[5] = (_Float16)hi.y;
            h[6] = (_Float16)hi.z; h[7] = (_Float16)hi.w;
            af[kc] = h;
        }
    } else {
        const _Float16* A = (const _Float16*)Av;
        int c0 = quad >> 1, qh = quad & 1;
#pragma unroll
        for (int kc = 0; kc < 4; ++kc) {
            size_t idx = ((size_t)(2 * kc + c0) * (n + 1) + arowc) * 16 + qh * 8;
            af[kc] = *(const half8*)(A + idx);
        }
    }

    f32x4 acc[8];
#pragma unroll
    for (int ct = 0; ct < 8; ++ct) acc[ct] = (f32x4){0.f, 0.f, 0.f, 0.f};

#pragma unroll
    for (int kc = 0; kc < 4; ++kc) {
#pragma unroll
        for (int ct = 0; ct < 8; ++ct) {
            half8 bf = *(half8*)&sW[(kc * 8 + ct) * 64 + lane];
            acc[ct] = __builtin_amdgcn_mfma_f32_16x16x32_f16(af[kc], bf, acc[ct], 0, 0, 0);
        }
    }

    __syncthreads();

    _Float16* eb = (_Float16*)smem + wave * 16 * 136;   // 136 halfs = 272 B row stride
    float dv[4];
#pragma unroll
    for (int r = 0; r < 4; ++r) {
        int rr = row0 + quad * 4 + r;
        dv[r] = dinv[(rr < n) ? rr : (n - 1)];
    }
#pragma unroll
    for (int ct = 0; ct < 8; ++ct)
#pragma unroll
        for (int r = 0; r < 4; ++r)
            eb[(quad * 4 + r) * 136 + ct * 16 + l16] = (_Float16)(acc[ct][r] * dv[r]);

    // chunk-major writeback: per row, 8 chunks x 32 B (4 x uint2 each)
#pragma unroll
    for (int i = 0; i < 8; ++i) {
        int u = i * 64 + lane;          // 512 units of 8 B over 16 rows
        int r = u >> 5;                 // row in wave tile
        int b = u & 31;                 // 8 B unit within row
        int c = b >> 2, h = b & 3;
        uint2 v = *(uint2*)((char*)eb + r * 272 + b * 8);
        int row = row0 + r;
        if (row < n) C[((size_t)c * (n + 1) + row) * 4 + h] = v;
    }
}

// ---------------- feature-chunked CSR aggregation + bias + ReLU + BN ----------------
// gridDim.y = chunk c (NCH). 8 lanes per node, 4 B (2 f16 features) per lane.
// Per-chunk gather buffer = (n+1)*32 B ~= 3.2 MB -> fits per-XCD L2.

template <bool FUSE_CLS>
__global__ __launch_bounds__(256) void k_aggregate(const unsigned int* __restrict__ Ah,
                                                   const int* __restrict__ offs,
                                                   const int* __restrict__ er,
                                                   const float* __restrict__ dinv,
                                                   const float* __restrict__ bias,
                                                   const float* __restrict__ g,
                                                   const float* __restrict__ be,
                                                   const float* __restrict__ rm,
                                                   const float* __restrict__ rv,
                                                   unsigned int* __restrict__ Hout,
                                                   const float* __restrict__ Wc,
                                                   float2* __restrict__ partials,
                                                   int n) {
    int c = blockIdx.y;
    int sub = threadIdx.x & 7;
    int node = blockIdx.x * 32 + (threadIdx.x >> 3);
    if (node >= n) return;
    size_t cbase = (size_t)c * (n + 1);

    float a0, a1;
    {   // self row (already scaled by dinv[node] in GEMM)
        unsigned q = Ah[(cbase + node) * 8 + sub];
        float2 f = __half22float2(*(__half2*)&q);
        a0 = f.x; a1 = f.y;
    }

    int e0 = offs[node], e1 = offs[node + 1];
    for (int e = e0; e < e1; e += 8) {
        int4 ra = *(const int4*)(er + e);
        int4 rb = *(const int4*)(er + e + 4);
        unsigned q0 = Ah[(cbase + ra.x) * 8 + sub];
        unsigned q1 = Ah[(cbase + ra.y) * 8 + sub];
        unsigned q2 = Ah[(cbase + ra.z) * 8 + sub];
        unsigned q3 = Ah[(cbase + ra.w) * 8 + sub];
        unsigned q4 = Ah[(cbase + rb.x) * 8 + sub];
        unsigned q5 = Ah[(cbase + rb.y) * 8 + sub];
        unsigned q6 = Ah[(cbase + rb.z) * 8 + sub];
        unsigned q7 = Ah[(cbase + rb.w) * 8 + sub];
        float2 f0 = __half22float2(*(__half2*)&q0);
        float2 f1 = __half22float2(*(__half2*)&q1);
        float2 f2 = __half22float2(*(__half2*)&q2);
        float2 f3 = __half22float2(*(__half2*)&q3);
        float2 f4 = __half22float2(*(__half2*)&q4);
        float2 f5 = __half22float2(*(__half2*)&q5);
        float2 f6 = __half22float2(*(__half2*)&q6);
        float2 f7 = __half22float2(*(__half2*)&q7);
        a0 += f0.x + f1.x + f2.x + f3.x + f4.x + f5.x + f6.x + f7.x;
        a1 += f0.y + f1.y + f2.y + f3.y + f4.y + f5.y + f6.y + f7.y;
    }

    float di = dinv[node];
    a0 *= di; a1 *= di;

    int fi = c * 8 + sub;   // float2 index over the 128 features
    float2 bb = ((const float2*)bias)[fi];
    float2 gg = ((const float2*)g)[fi];
    float2 ee = ((const float2*)be)[fi];
    float2 mm = ((const float2*)rm)[fi];
    float2 vv = ((const float2*)rv)[fi];

    float v0 = fmaxf(a0 + bb.x, 0.f);
    float v1 = fmaxf(a1 + bb.y, 0.f);
    float o0 = (v0 - mm.x) * rsqrtf(vv.x + BN_EPS) * gg.x + ee.x;
    float o1 = (v1 - mm.y) * rsqrtf(vv.y + BN_EPS) * gg.y + ee.y;

    if (!FUSE_CLS) {
        __half2 p = __floats2half2_rn(o0, o1);
        Hout[(cbase + node) * 8 + sub] = *(unsigned int*)&p;
    } else {
        float4 w = ((const float4*)Wc)[fi];   // (Wc[f0][0],Wc[f0][1],Wc[f1][0],Wc[f1][1])
        float p0 = o0 * w.x + o1 * w.z;
        float p1 = o0 * w.y + o1 * w.w;
#pragma unroll
        for (int d = 4; d >= 1; d >>= 1) {
            p0 += __shfl_down(p0, d, 8);
            p1 += __shfl_down(p1, d, 8);
        }
        if (sub == 0) partials[(size_t)c * n + node] = make_float2(p0, p1);
    }
}

__global__ __launch_bounds__(256) void k_reduce_out(const float2* __restrict__ partials,
                                                    const float* __restrict__ bc,
                                                    float2* __restrict__ out2, int n) {
    int i = blockIdx.x * 256 + threadIdx.x;
    if (i >= n) return;
    float sx = 0.f, sy = 0.f;
#pragma unroll
    for (int c = 0; c < NCH; ++c) {
        float2 p = partials[(size_t)c * n + i];
        sx += p.x; sy += p.y;
    }
    out2[i] = make_float2(sx + bc[0], sy + bc[1]);
}

// ---------------- launch ----------------

extern "C" void kernel_launch(void* const* d_in, const int* in_sizes, int n_in,
                              void* d_out, int out_size, void* d_ws, size_t ws_size,
                              hipStream_t stream) {
    const float* x   = (const float*)d_in[0];
    const int*   ei  = (const int*)d_in[1];
    const float* W1  = (const float*)d_in[2];
    const float* b1  = (const float*)d_in[3];
    const float* W2  = (const float*)d_in[4];
    const float* b2  = (const float*)d_in[5];
    const float* W3  = (const float*)d_in[6];
    const float* b3  = (const float*)d_in[7];
    const float* g1  = (const float*)d_in[8];
    const float* be1 = (const float*)d_in[9];
    const float* rm1 = (const float*)d_in[10];
    const float* rv1 = (const float*)d_in[11];
    const float* g2  = (const float*)d_in[12];
    const float* be2 = (const float*)d_in[13];
    const float* rm2 = (const float*)d_in[14];
    const float* rv2 = (const float*)d_in[15];
    const float* g3  = (const float*)d_in[16];
    const float* be3 = (const float*)d_in[17];
    const float* rm3 = (const float*)d_in[18];
    const float* rv3 = (const float*)d_in[19];
    const float* Wc  = (const float*)d_in[20];
    const float* bc  = (const float*)d_in[21];
    float* out = (float*)d_out;

    int n = in_sizes[0] / 128;
    int e = in_sizes[1] / 2;
    const int* src = ei;
    const int* dst = ei + e;

    char* ws = (char*)d_ws;
    size_t off = 0;
    auto alloc = [&](size_t bytes) -> char* {
        char* p = ws + off;
        off += (bytes + 255) & ~(size_t)255;
        return p;
    };
    int erCap = e + 8 * n;
    char*      bufA   = (char*) alloc((size_t)(n + 1) * 128 * 2);  // GEMM out f16 chunk-major
    char*      bufH   = (char*) alloc((size_t)(n + 1) * 128 * 2 + 64); // H f16 chunk-major / partials / prep alias
    char*      scr    = (char*) alloc((size_t)20 * 1024 * 1024);   // prep scratch
    float*     dinv   = (float*)alloc((size_t)n * 4);
    int*       counts = (int*)  alloc((size_t)n * 4);
    int*       offs   = (int*)  alloc((size_t)(n + 1) * 4);
    int*       parts  = (int*)  alloc(8192);
    int*       er     = (int*)  alloc((size_t)erCap * 4);
    _Float16*  pW     = (_Float16*)alloc(3 * 16384 * 2);
    (void)ws_size; (void)n_in; (void)out_size;

    int nA    = (e + CHUNK - 1) / CHUNK;
    int nbuck = (n + (1 << BBITS) - 1) >> BBITS;
    int tlen  = nbuck * nA;
    {
        char* p = scr;
        size_t po = 0;
        auto palloc = [&](size_t bytes) -> char* {
            char* q = p + po;
            po += (bytes + 255) & ~(size_t)255;
            return q;
        };
        // scratch: e*8 + e*4 + tlen*4 = 12.8 + 6.4 + ~2.5 MB < 20 MB... bed/brank fit:
        int2* bed    = (int2*)palloc((size_t)e * 8);
        int*  brank  = (int*) p;   // alias AFTER bed is consumed? NO - needed simultaneously.
        // brank + tableT go into bufH region (dead until first aggregate)
        {
            char* p2 = bufH;
            size_t po2 = 0;
            auto palloc2 = [&](size_t bytes) -> char* {
                char* q = p2 + po2;
                po2 += (bytes + 255) & ~(size_t)255;
                return q;
            };
            brank = (int*)palloc2((size_t)e * 4);
            int* tableT = (int*)palloc2((size_t)(tlen + 1) * 4);

            k_zero_pad<<<1, 64, 0, stream>>>((unsigned int*)bufA, n);

            int gN  = (n + 255) / 256;
            int nb  = (n + 1023) / 1024;
            int nbT = (tlen + 1023) / 1024;
            int m4  = erCap / 4;

            k_packW<<<8, 256, 0, stream>>>(W1, pW);
            k_packW<<<8, 256, 0, stream>>>(W2, pW + 16384);
            k_packW<<<8, 256, 0, stream>>>(W3, pW + 32768);
            k_bucket_hist<<<nA, 256, 0, stream>>>(dst, tableT, nA, nbuck, e);
            k_scan_block<false><<<nbT, 1024, 0, stream>>>(tableT, tableT, parts, tlen);
            k_scan_partials<<<1, 1024, 0, stream>>>(parts, nbT);
            k_scan_add<<<(tlen + 255) / 256, 256, 0, stream>>>(tableT, parts, tlen);
            k_bucket_scatter<<<nA, 256, 0, stream>>>(src, dst, tableT, bed, nA, nbuck, e);
            k_bucket_rank<<<nbuck, 256, 0, stream>>>(bed, tableT, brank, counts, dinv, nA, nbuck, n, e);
            k_scan_block<true><<<nb, 1024, 0, stream>>>(counts, offs, parts, n);
            k_scan_partials<<<1, 1024, 0, stream>>>(parts, nb);
            k_scan_add<<<gN, 256, 0, stream>>>(offs, parts, n);
            k_fill<<<(m4 + 255) / 256, 256, 0, stream>>>((int4*)er, n, m4);
            k_place2<<<((e + 1) / 2 + 255) / 256, 256, 0, stream>>>(bed, brank, offs, er, e);
        }
    }

    int gGemm = (n + 63) / 64;
    dim3 gAgg((n + 31) / 32, NCH);

    k_gemm_mfma<true><<<gGemm, 256, 0, stream>>>(x, pW, dinv, (uint2*)bufA, n);
    k_aggregate<false><<<gAgg, 256, 0, stream>>>((const unsigned int*)bufA, offs, er, dinv,
                                                 b1, g1, be1, rm1, rv1,
                                                 (unsigned int*)bufH, nullptr, nullptr, n);

    k_gemm_mfma<false><<<gGemm, 256, 0, stream>>>(bufH, pW + 16384, dinv, (uint2*)bufA, n);
    k_aggregate<false><<<gAgg, 256, 0, stream>>>((const unsigned int*)bufA, offs, er, dinv,
                                                 b2, g2, be2, rm2, rv2,
                                                 (unsigned int*)bufH, nullptr, nullptr, n);

    k_gemm_mfma<false><<<gGemm, 256, 0, stream>>>(bufH, pW + 32768, dinv, (uint2*)bufA, n);
    // layer 3: H region is dead -> reuse bufH as classifier partials [NCH][n] float2
    float2* partials = (float2*)bufH;
    k_aggregate<true><<<gAgg, 256, 0, stream>>>((const unsigned int*)bufA, offs, er, dinv,
                                                b3, g3, be3, rm3, rv3,
                                                nullptr, Wc, partials, n);
    k_reduce_out<<<(n + 255) / 256, 256, 0, stream>>>(partials, bc, (float2*)out, n);
}